// Round 3
// baseline (5509.171 us; speedup 1.0000x reference)
//
#include <hip/hip_runtime.h>
#include <hip/hip_bf16.h>
#include <math.h>

#define Bc 128
#define Tc 128
#define Hc 768
#define NHEAD 12
#define DKc 64
#define RINc 512
#define RHc 512
#define G4c 2048
#define NTc 10
#define LNEPS 1e-5f

__device__ __forceinline__ float sigmoidf_(float x) { return 1.0f / (1.0f + expf(-x)); }

__global__ void bias_sum_k(const float* __restrict__ a, const float* __restrict__ b,
                           float* __restrict__ o) {
  int i = blockIdx.x * blockDim.x + threadIdx.x;
  if (i < G4c) o[i] = a[i] + b[i];
}

// C[M,N] = act(A[M,K] @ W[N,K]^T + bias), 128x128 tile, 8x8 micro, BK=8
// amode==1: A row m=(tl*128+b) is virtual concat: k<768 -> utt[b, trow0+tl, k], else Xo[b,k-768]
__global__ __launch_bounds__(256) void sgemm_bt(
    const float* __restrict__ A, const float* __restrict__ W,
    const float* __restrict__ bias, float* __restrict__ C,
    int M, int N, int K, int amode, int act,
    const float* __restrict__ utt, const float* __restrict__ xo, int trow0)
{
  __shared__ float As[8][128];
  __shared__ float Bs[8][128];
  const int tid = threadIdx.x;
  const int tx = tid & 15, ty = tid >> 4;
  const int row0 = blockIdx.y * 128, col0 = blockIdx.x * 128;
  float acc[8][8];
#pragma unroll
  for (int i = 0; i < 8; ++i)
#pragma unroll
    for (int j = 0; j < 8; ++j) acc[i][j] = 0.f;

  const int r = tid >> 1;
  const int kq = (tid & 1) << 2;
  for (int kb = 0; kb < K; kb += 8) {
    float4 av, bv;
    {
      const int m = row0 + r;
      const int k = kb + kq;
      if (amode == 0) {
        av = *(const float4*)(A + (size_t)m * K + k);
      } else {
        const int t = trow0 + (m >> 7), b = m & 127;
        av = (k < Hc) ? *(const float4*)(utt + ((size_t)b * Tc + t) * Hc + k)
                      : *(const float4*)(xo + (size_t)b * Hc + (k - Hc));
      }
      bv = *(const float4*)(W + (size_t)(col0 + r) * K + k);
    }
    As[kq + 0][r] = av.x; As[kq + 1][r] = av.y; As[kq + 2][r] = av.z; As[kq + 3][r] = av.w;
    Bs[kq + 0][r] = bv.x; Bs[kq + 1][r] = bv.y; Bs[kq + 2][r] = bv.z; Bs[kq + 3][r] = bv.w;
    __syncthreads();
#pragma unroll
    for (int k = 0; k < 8; ++k) {
      const float4 a0 = *(const float4*)&As[k][ty * 8];
      const float4 a1 = *(const float4*)&As[k][ty * 8 + 4];
      const float4 b0 = *(const float4*)&Bs[k][tx * 8];
      const float4 b1 = *(const float4*)&Bs[k][tx * 8 + 4];
      const float am[8] = {a0.x, a0.y, a0.z, a0.w, a1.x, a1.y, a1.z, a1.w};
      const float bn[8] = {b0.x, b0.y, b0.z, b0.w, b1.x, b1.y, b1.z, b1.w};
#pragma unroll
      for (int i = 0; i < 8; ++i)
#pragma unroll
        for (int j = 0; j < 8; ++j)
          acc[i][j] = fmaf(am[i], bn[j], acc[i][j]);
    }
    __syncthreads();
  }
#pragma unroll
  for (int i = 0; i < 8; ++i) {
    const int m = row0 + ty * 8 + i;
#pragma unroll
    for (int j4 = 0; j4 < 8; j4 += 4) {
      const int n = col0 + tx * 8 + j4;
      float4 o;
      o.x = acc[i][j4 + 0] + bias[n + 0];
      o.y = acc[i][j4 + 1] + bias[n + 1];
      o.z = acc[i][j4 + 2] + bias[n + 2];
      o.w = acc[i][j4 + 3] + bias[n + 3];
      if (act == 1) { o.x = sigmoidf_(o.x); o.y = sigmoidf_(o.y); o.z = sigmoidf_(o.z); o.w = sigmoidf_(o.w); }
      *(float4*)(C + (size_t)m * N + n) = o;
    }
  }
}

// block per b, 128 threads. Fused: P[h,:] = Q[b,h*64+:].Wk slice; scores; softmax -> Att
__global__ __launch_bounds__(128) void attn_scores_k(
    const float* __restrict__ Q, const float* __restrict__ Wk,
    const float* __restrict__ bk, const float* __restrict__ utt,
    float* __restrict__ Att)
{
  __shared__ float qs[Hc];          // 3 KB
  __shared__ float Ps[NHEAD][Hc];   // 36.9 KB
  __shared__ float cqs[NHEAD];
  __shared__ float sc[NHEAD][Tc];   // 6 KB
  __shared__ float rd[Tc];
  const int b = blockIdx.x;
  const int t = threadIdx.x;
  for (int i = t; i < Hc; i += 128) qs[i] = Q[(size_t)b * Hc + i];
  __syncthreads();
  // P[h][j]
  for (int idx = t; idx < NHEAD * Hc; idx += 128) {
    const int h = idx / Hc, j = idx - h * Hc;
    const float* wb = Wk + (size_t)(h * DKc) * Hc + j;
    const float* qb = qs + h * DKc;
    float a = 0.f;
#pragma unroll 8
    for (int d = 0; d < DKc; ++d) a = fmaf(qb[d], wb[(size_t)d * Hc], a);
    Ps[h][j] = a;
  }
  if (t < NHEAD) {
    float a = 0.f;
#pragma unroll 8
    for (int d = 0; d < DKc; ++d) a = fmaf(qs[t * DKc + d], bk[t * DKc + d], a);
    cqs[t] = a;
  }
  __syncthreads();
  // scores for this thread's key t
  float acc[NHEAD];
#pragma unroll
  for (int h = 0; h < NHEAD; ++h) acc[h] = 0.f;
  const float* xr = utt + ((size_t)b * Tc + t) * Hc;
  for (int j = 0; j < Hc; j += 4) {
    const float4 xv = *(const float4*)(xr + j);
#pragma unroll
    for (int h = 0; h < NHEAD; ++h)
      acc[h] += xv.x * Ps[h][j] + xv.y * Ps[h][j + 1] + xv.z * Ps[h][j + 2] + xv.w * Ps[h][j + 3];
  }
#pragma unroll
  for (int h = 0; h < NHEAD; ++h) sc[h][t] = (acc[h] + cqs[h]) * 0.125f;
  __syncthreads();
  for (int h = 0; h < NHEAD; ++h) {
    rd[t] = sc[h][t];
    __syncthreads();
    for (int off = 64; off > 0; off >>= 1) {
      if (t < off) rd[t] = fmaxf(rd[t], rd[t + off]);
      __syncthreads();
    }
    const float mx = rd[0];
    __syncthreads();
    const float e = expf(sc[h][t] - mx);
    rd[t] = e;
    __syncthreads();
    for (int off = 64; off > 0; off >>= 1) {
      if (t < off) rd[t] += rd[t + off];
      __syncthreads();
    }
    Att[((size_t)b * NHEAD + h) * Tc + t] = e / rd[0];
    __syncthreads();
  }
}

// block per b, 256 threads: U (LDS) = sum_t Att*utt; Xc = Wv.U + bv
__global__ __launch_bounds__(256) void attn_uxc_k(
    const float* __restrict__ Att, const float* __restrict__ utt,
    const float* __restrict__ Wv, const float* __restrict__ bv,
    float* __restrict__ Xc)
{
  __shared__ float As[NHEAD][Tc];   // 6 KB
  __shared__ float Us[NHEAD * Hc];  // 36.9 KB
  const int b = blockIdx.x;
  const int tid = threadIdx.x;
  for (int i = tid; i < NHEAD * Tc; i += 256)
    ((float*)As)[i] = Att[(size_t)b * NHEAD * Tc + i];
  __syncthreads();
  float acc[NHEAD][3];
#pragma unroll
  for (int h = 0; h < NHEAD; ++h)
#pragma unroll
    for (int q = 0; q < 3; ++q) acc[h][q] = 0.f;
  for (int t = 0; t < Tc; ++t) {
    const float* xr = utt + ((size_t)b * Tc + t) * Hc;
    const float x0 = xr[tid], x1 = xr[tid + 256], x2 = xr[tid + 512];
#pragma unroll
    for (int h = 0; h < NHEAD; ++h) {
      const float a = As[h][t];
      acc[h][0] = fmaf(a, x0, acc[h][0]);
      acc[h][1] = fmaf(a, x1, acc[h][1]);
      acc[h][2] = fmaf(a, x2, acc[h][2]);
    }
  }
#pragma unroll
  for (int h = 0; h < NHEAD; ++h)
#pragma unroll
    for (int q = 0; q < 3; ++q)
      Us[h * Hc + tid + q * 256] = acc[h][q];
  __syncthreads();
#pragma unroll
  for (int r = 0; r < 3; ++r) {
    const int hd = tid + r * 256;
    const int h = hd >> 6;
    const float* wr = Wv + (size_t)hd * Hc;
    const float* ub = Us + h * Hc;
    float a = 0.f;
    for (int j = 0; j < Hc; j += 4) {
      const float4 w4 = *(const float4*)(wr + j);
      a += w4.x * ub[j] + w4.y * ub[j + 1] + w4.z * ub[j + 2] + w4.w * ub[j + 3];
    }
    Xc[(size_t)b * Hc + hd] = a + bv[hd];
  }
}

// 256 blocks x 512 thr; block=(bt 0..7 [16 batches], ut 0..31 [16 units]);
// thread = (kh, bl, ul): one (b,u) pair with K split across kh=0/1.
// GXc/Hch are chunk-local (row tl). h ping-pong fp32 (global t parity).
__global__ __launch_bounds__(512) void lstm_step_k(
    const float* __restrict__ Whh, const float* __restrict__ GXc,
    float* __restrict__ Hping, __hip_bfloat16* __restrict__ Hch,
    float* __restrict__ Cb, int t, int tl)
{
  __shared__ float hs[RHc * 16];    // k-major: hs[k*16 + bl]  (32 KB)
  __shared__ float red[2 * 256 * 4];
  const int blk = blockIdx.x;
  const int ut = blk & 31, bt = blk >> 5;
  const int tid = threadIdx.x;
  const int kh = tid >> 8;
  const int p = tid & 255;
  const int bl = p & 15, ul = p >> 4;
  const int b = bt * 16 + bl, u = ut * 16 + ul;
  float ai = 0.f, af = 0.f, ag = 0.f, ao = 0.f;
  if (t > 0) {
    const float* hprev = Hping + (size_t)((t & 1) ^ 1) * (Bc * RHc) + (size_t)(bt * 16) * RHc;
#pragma unroll
    for (int i = 0; i < 4; ++i) {
      const int idx = tid + i * 512;
      const int rr = idx & 15;
      const int c4 = (idx >> 4) << 2;
      const float4 hv = *(const float4*)(hprev + (size_t)rr * RHc + c4);
      hs[(c4 + 0) * 16 + rr] = hv.x;
      hs[(c4 + 1) * 16 + rr] = hv.y;
      hs[(c4 + 2) * 16 + rr] = hv.z;
      hs[(c4 + 3) * 16 + rr] = hv.w;
    }
    __syncthreads();
    const float* w0 = Whh + (size_t)u * RHc + kh * 256;
    const float* w1 = w0 + 512 * 512;
    const float* w2 = w1 + 512 * 512;
    const float* w3 = w2 + 512 * 512;
    const int hb = (kh * 256) * 16 + bl;
#pragma unroll 4
    for (int kk = 0; kk < 256; kk += 4) {
      const float4 wi = *(const float4*)(w0 + kk);
      const float4 wf = *(const float4*)(w1 + kk);
      const float4 wg = *(const float4*)(w2 + kk);
      const float4 wo = *(const float4*)(w3 + kk);
      const int hk = hb + kk * 16;
      const float h0 = hs[hk], h1 = hs[hk + 16], h2 = hs[hk + 32], h3 = hs[hk + 48];
      ai = fmaf(wi.x, h0, fmaf(wi.y, h1, fmaf(wi.z, h2, fmaf(wi.w, h3, ai))));
      af = fmaf(wf.x, h0, fmaf(wf.y, h1, fmaf(wf.z, h2, fmaf(wf.w, h3, af))));
      ag = fmaf(wg.x, h0, fmaf(wg.y, h1, fmaf(wg.z, h2, fmaf(wg.w, h3, ag))));
      ao = fmaf(wo.x, h0, fmaf(wo.y, h1, fmaf(wo.z, h2, fmaf(wo.w, h3, ao))));
    }
  }
  *(float4*)&red[((size_t)kh * 256 + p) * 4] = make_float4(ai, af, ag, ao);
  __syncthreads();
  if (kh == 0) {
    const float4 oth = *(const float4*)&red[(size_t)(256 + p) * 4];
    ai += oth.x; af += oth.y; ag += oth.z; ao += oth.w;
    const size_t gofs = ((size_t)tl * Bc + b) * G4c + u;
    const float gi = GXc[gofs] + ai;
    const float gf = GXc[gofs + 512] + af;
    const float gg = GXc[gofs + 1024] + ag;
    const float go = GXc[gofs + 1536] + ao;
    const float iv = sigmoidf_(gi);
    const float fv = sigmoidf_(gf);
    const float gv = tanhf(gg);
    const float ov = sigmoidf_(go);
    const size_t cidx = (size_t)b * RHc + u;
    float c = (t > 0) ? Cb[cidx] : 0.f;
    c = fmaf(fv, c, iv * gv);
    Cb[cidx] = c;
    const float hval = ov * tanhf(c);
    Hping[(size_t)(t & 1) * (Bc * RHc) + (size_t)b * RHc + u] = hval;
    Hch[((size_t)tl * Bc + b) * RHc + u] = __float2bfloat16(hval);
  }
}

// one wave per (tl,b) of the chunk: y = h @ W_tag^T + b_tag, LayerNorm over NT=10
__global__ __launch_bounds__(256) void tag_ln_k(
    const __hip_bfloat16* __restrict__ Hch, const float* __restrict__ Wtag,
    const float* __restrict__ btag, const float* __restrict__ lng,
    const float* __restrict__ lnb, float* __restrict__ out, int t0)
{
  const int wid = (blockIdx.x * blockDim.x + threadIdx.x) >> 6;
  const int lane = threadIdx.x & 63;
  const int tl = wid >> 7, b = wid & 127;
  const int t = t0 + tl;
  const __hip_bfloat16* hp = Hch + ((size_t)tl * Bc + b) * RHc;
  float y[NTc];
#pragma unroll
  for (int j = 0; j < NTc; ++j) y[j] = 0.f;
  for (int k = lane; k < RHc; k += 64) {
    const float hv = __bfloat162float(hp[k]);
#pragma unroll
    for (int j = 0; j < NTc; ++j)
      y[j] = fmaf(hv, Wtag[(size_t)j * RHc + k], y[j]);
  }
#pragma unroll
  for (int off = 32; off > 0; off >>= 1)
#pragma unroll
    for (int j = 0; j < NTc; ++j)
      y[j] += __shfl_xor(y[j], off);
  float mu = 0.f;
#pragma unroll
  for (int j = 0; j < NTc; ++j) { y[j] += btag[j]; mu += y[j]; }
  mu *= (1.0f / NTc);
  float var = 0.f;
#pragma unroll
  for (int j = 0; j < NTc; ++j) { const float d = y[j] - mu; var = fmaf(d, d, var); }
  var *= (1.0f / NTc);
  const float inv = rsqrtf(var + LNEPS);
  if (lane < NTc) {
    out[(size_t)b * NTc * Tc + (size_t)lane * Tc + t] =
        (y[lane] - mu) * inv * lng[lane] + lnb[lane];
  }
}

extern "C" void kernel_launch(void* const* d_in, const int* in_sizes, int n_in,
                              void* d_out, int out_size, void* d_ws, size_t ws_size,
                              hipStream_t stream)
{
  const float* slot = (const float*)d_in[0];
  const float* utt  = (const float*)d_in[1];
  const float* Wq = (const float*)d_in[2];   const float* bq = (const float*)d_in[3];
  const float* Wk = (const float*)d_in[4];   const float* bk = (const float*)d_in[5];
  const float* Wv = (const float*)d_in[6];   const float* bv = (const float*)d_in[7];
  const float* Wo = (const float*)d_in[8];   const float* bo = (const float*)d_in[9];
  const float* W_in = (const float*)d_in[10]; const float* b_in = (const float*)d_in[11];
  const float* W_ih = (const float*)d_in[12]; const float* W_hh = (const float*)d_in[13];
  const float* b_ih = (const float*)d_in[14]; const float* b_hh = (const float*)d_in[15];
  const float* W_tag = (const float*)d_in[16]; const float* b_tag = (const float*)d_in[17];
  const float* ln_g = (const float*)d_in[18]; const float* ln_b = (const float*)d_in[19];
  float* out = (float*)d_out;
  float* ws = (float*)d_ws;

  // adaptive chunk size from ws_size (deterministic: ws_size is fixed per session)
  // bytes(CHT) = 4 * (690176 fixed floats + 360448 * CHT)
  int CHT = 16;
  while (CHT > 1 && sizeof(float) * (690176ull + 360448ull * (unsigned)CHT) > ws_size)
    CHT >>= 1;
  const int NCH = Tc / CHT;

  // workspace layout (floats)
  float* Qb    = ws;                    // 98304
  float* Xc    = Qb + 98304;            // 98304
  float* Xo    = Xc + 98304;            // 98304
  float* bsum  = Xo + 98304;            // 2048
  float* Cb    = bsum + 2048;           // 65536
  float* Att   = Cb + 65536;            // 196608 (128*12*128)
  float* Hping = Att + 196608;          // 131072 (2*128*512)
  float* LINc  = Hping + 131072;        // 65536*CHT
  float* GXc   = LINc + (size_t)65536 * CHT;   // 262144*CHT
  __hip_bfloat16* Hch = (__hip_bfloat16*)(GXc + (size_t)262144 * CHT);  // 65536*CHT bf16

  hipLaunchKernelGGL(bias_sum_k, dim3(8), dim3(256), 0, stream, b_ih, b_hh, bsum);
  // Q = slot @ Wq^T + bq
  hipLaunchKernelGGL(sgemm_bt, dim3(6, 1), dim3(256), 0, stream,
                     slot, Wq, bq, Qb, 128, 768, 768, 0, 0,
                     (const float*)nullptr, (const float*)nullptr, 0);
  // fused fold-q + scores + softmax -> Att
  hipLaunchKernelGGL(attn_scores_k, dim3(Bc), dim3(128), 0, stream, Qb, Wk, bk, utt, Att);
  // fused U + Xc
  hipLaunchKernelGGL(attn_uxc_k, dim3(Bc), dim3(256), 0, stream, Att, utt, Wv, bv, Xc);
  // Xo = Xc @ Wo^T + bo
  hipLaunchKernelGGL(sgemm_bt, dim3(6, 1), dim3(256), 0, stream,
                     Xc, Wo, bo, Xo, 128, 768, 768, 0, 0,
                     (const float*)nullptr, (const float*)nullptr, 0);

  // chunked precompute + sequential LSTM + chunked tag/LN
  for (int tc = 0; tc < NCH; ++tc) {
    hipLaunchKernelGGL(sgemm_bt, dim3(4, CHT), dim3(256), 0, stream,
                       (const float*)nullptr, W_in, b_in, LINc,
                       CHT * Bc, 512, 1536, 1, 1, utt, Xo, tc * CHT);
    hipLaunchKernelGGL(sgemm_bt, dim3(16, CHT), dim3(256), 0, stream,
                       LINc, W_ih, bsum, GXc, CHT * Bc, 2048, 512, 0, 0,
                       (const float*)nullptr, (const float*)nullptr, 0);
    for (int tl = 0; tl < CHT; ++tl)
      hipLaunchKernelGGL(lstm_step_k, dim3(256), dim3(512), 0, stream,
                         W_hh, GXc, Hping, Hch, Cb, tc * CHT + tl, tl);
    hipLaunchKernelGGL(tag_ln_k, dim3(CHT * 32), dim3(256), 0, stream,
                       Hch, W_tag, b_tag, ln_g, ln_b, out, tc * CHT);
  }
}

// Round 4
// 3452.183 us; speedup vs baseline: 1.5959x; 1.5959x over previous
//
#include <hip/hip_runtime.h>
#include <hip/hip_bf16.h>
#include <math.h>

#define Bc 128
#define Tc 128
#define Hc 768
#define NHEAD 12
#define DKc 64
#define RHc 512
#define G4c 2048
#define NTc 10
#define LNEPS 1e-5f

typedef short bf16x8 __attribute__((ext_vector_type(8)));
typedef float f32x4 __attribute__((ext_vector_type(4)));

__device__ __forceinline__ float sigmoidf_(float x) { return 1.0f / (1.0f + expf(-x)); }

__device__ __forceinline__ ushort f2bf(float f) {
  union { float f; uint u; } c; c.f = f;
  uint r = (c.u + 0x7FFFu + ((c.u >> 16) & 1u)) >> 16;
  return (ushort)r;
}
__device__ __forceinline__ float bf2f(ushort u) {
  union { uint u; float f; } c; c.u = ((uint)u) << 16;
  return c.f;
}
__device__ __forceinline__ uint pack2(float a, float b) {
  return (uint)f2bf(a) | ((uint)f2bf(b) << 16);
}

__global__ void bias_sum_k(const float* __restrict__ a, const float* __restrict__ b,
                           float* __restrict__ o) {
  int i = blockIdx.x * blockDim.x + threadIdx.x;
  if (i < G4c) o[i] = a[i] + b[i];
}

__global__ void cvt4_k(const float* __restrict__ x, ushort* __restrict__ y, int n4) {
  int i = blockIdx.x * 256 + threadIdx.x;
  if (i < n4) {
    float4 v = ((const float4*)x)[i];
    ushort4 o; o.x = f2bf(v.x); o.y = f2bf(v.y); o.z = f2bf(v.z); o.w = f2bf(v.w);
    ((ushort4*)y)[i] = o;
  }
}

// ---------------- bf16 MFMA GEMM: C = act(A @ Wb^T + bias) ----------------
// 128x128 tile, 4 waves (2x2), each wave 64x64 via 4x4 frags of 16x16x32.
// amode: 0 = A fp32 [M][K]; 1 = virtual concat (utt/xo fp32, row m=(by*128+r));
//        2 = A bf16 [M][K].
// outMode: 0 = fp32 + bias; 1 = sigmoid -> bf16 + bias.
__global__ __launch_bounds__(256) void bgemm_bt(
    const void* __restrict__ Aptr, const ushort* __restrict__ Wb,
    const float* __restrict__ bias, void* __restrict__ Cptr,
    int M, int N, int K, int amode, int outMode,
    const float* __restrict__ utt, const float* __restrict__ xo, int trow0)
{
  __shared__ ushort As[128 * 40];   // pad stride 40 (80 B) -> ~2-way banks
  __shared__ ushort Ws[128 * 40];
  const int tid = threadIdx.x;
  const int lane = tid & 63, wid = tid >> 6;
  const int wm = wid >> 1, wn = wid & 1;
  const int row0 = blockIdx.y * 128, col0 = blockIdx.x * 128;

  f32x4 acc[4][4];
#pragma unroll
  for (int i = 0; i < 4; ++i)
#pragma unroll
    for (int j = 0; j < 4; ++j) {
      f32x4 z = {0.f, 0.f, 0.f, 0.f};
      acc[i][j] = z;
    }

  const int r = tid >> 1, kq = (tid & 1) * 16;

  for (int kb = 0; kb < K; kb += 32) {
    const int k = kb + kq;
    // stage A tile (128 x 32)
    if (amode == 2) {
      const ushort* ap = (const ushort*)Aptr + (size_t)(row0 + r) * K + k;
      *(uint4*)&As[r * 40 + kq] = *(const uint4*)ap;
      *(uint4*)&As[r * 40 + kq + 8] = *(const uint4*)(ap + 8);
    } else {
      const float* ap;
      if (amode == 0) {
        ap = (const float*)Aptr + (size_t)(row0 + r) * K + k;
      } else {
        const int b = r;
        const int t = trow0 + blockIdx.y;
        ap = (k < Hc) ? utt + ((size_t)b * Tc + t) * Hc + k
                      : xo + (size_t)b * Hc + (k - Hc);
      }
      const float4 f0 = *(const float4*)ap;
      const float4 f1 = *(const float4*)(ap + 4);
      const float4 f2 = *(const float4*)(ap + 8);
      const float4 f3 = *(const float4*)(ap + 12);
      uint4 u0, u1;
      u0.x = pack2(f0.x, f0.y); u0.y = pack2(f0.z, f0.w);
      u0.z = pack2(f1.x, f1.y); u0.w = pack2(f1.z, f1.w);
      u1.x = pack2(f2.x, f2.y); u1.y = pack2(f2.z, f2.w);
      u1.z = pack2(f3.x, f3.y); u1.w = pack2(f3.z, f3.w);
      *(uint4*)&As[r * 40 + kq] = u0;
      *(uint4*)&As[r * 40 + kq + 8] = u1;
    }
    // stage W tile (128 x 32), always bf16
    {
      const ushort* wp = Wb + (size_t)(col0 + r) * K + k;
      *(uint4*)&Ws[r * 40 + kq] = *(const uint4*)wp;
      *(uint4*)&Ws[r * 40 + kq + 8] = *(const uint4*)(wp + 8);
    }
    __syncthreads();
    const int koff = (lane >> 4) * 8;
    const int ar = wm * 64 + (lane & 15);
    const int wr = wn * 64 + (lane & 15);
    bf16x8 af[4], wf[4];
#pragma unroll
    for (int i = 0; i < 4; ++i) af[i] = *(const bf16x8*)&As[(ar + i * 16) * 40 + koff];
#pragma unroll
    for (int i = 0; i < 4; ++i) wf[i] = *(const bf16x8*)&Ws[(wr + i * 16) * 40 + koff];
#pragma unroll
    for (int fm = 0; fm < 4; ++fm)
#pragma unroll
      for (int fn = 0; fn < 4; ++fn)
        acc[fm][fn] = __builtin_amdgcn_mfma_f32_16x16x32_bf16(af[fm], wf[fn], acc[fm][fn], 0, 0, 0);
    __syncthreads();
  }

#pragma unroll
  for (int fm = 0; fm < 4; ++fm) {
    const int m0 = row0 + wm * 64 + fm * 16 + ((lane >> 4) * 4);
#pragma unroll
    for (int fn = 0; fn < 4; ++fn) {
      const int n = col0 + wn * 64 + fn * 16 + (lane & 15);
      const float bb = bias[n];
#pragma unroll
      for (int q = 0; q < 4; ++q) {
        const float v = acc[fm][fn][q] + bb;
        if (outMode == 1)
          ((ushort*)Cptr)[(size_t)(m0 + q) * N + n] = f2bf(sigmoidf_(v));
        else
          ((float*)Cptr)[(size_t)(m0 + q) * N + n] = v;
      }
    }
  }
}

// ------------- attention: fold q and P per (b,h); 1536 blocks -------------
__global__ __launch_bounds__(256) void fold_qp_k(
    const float* __restrict__ slot, const float* __restrict__ Wq,
    const float* __restrict__ bq, const float* __restrict__ Wk,
    const float* __restrict__ bk, ushort* __restrict__ Pb, float* __restrict__ cqB)
{
  __shared__ float ss[Hc];
  __shared__ float qp[4][DKc];
  __shared__ float qs[DKc];
  const int bx = blockIdx.x;
  const int b = bx / NHEAD, h = bx % NHEAD;
  const int tid = threadIdx.x;
  for (int i = tid; i < Hc; i += 256) ss[i] = slot[(size_t)b * Hc + i];
  __syncthreads();
  {
    const int d = tid & 63, qt = tid >> 6;
    const float* wr = Wq + (size_t)(h * DKc + d) * Hc + qt * 192;
    const float* sb = ss + qt * 192;
    float a = 0.f;
    for (int e = 0; e < 192; e += 4) {
      const float4 wv = *(const float4*)(wr + e);
      a += wv.x * sb[e] + wv.y * sb[e + 1] + wv.z * sb[e + 2] + wv.w * sb[e + 3];
    }
    qp[qt][d] = a;
  }
  __syncthreads();
  if (tid < DKc)
    qs[tid] = qp[0][tid] + qp[1][tid] + qp[2][tid] + qp[3][tid] + bq[h * DKc + tid];
  __syncthreads();
  if (tid < DKc) {
    float pv = qs[tid] * bk[h * DKc + tid];
#pragma unroll
    for (int off = 32; off; off >>= 1) pv += __shfl_xor(pv, off);
    if (tid == 0) cqB[b * NHEAD + h] = pv;
  }
  for (int j = tid; j < Hc; j += 256) {
    float a = 0.f;
#pragma unroll 8
    for (int d = 0; d < DKc; ++d)
      a = fmaf(qs[d], Wk[(size_t)(h * DKc + d) * Hc + j], a);
    Pb[((size_t)b * NHEAD + h) * Hc + j] = f2bf(a);
  }
}

// per-b scores + wave-shuffle softmax
__global__ __launch_bounds__(256) void attn_scores2_k(
    const ushort* __restrict__ Pb, const float* __restrict__ cqB,
    const float* __restrict__ utt, float* __restrict__ Att)
{
  __shared__ float Phs[NHEAD][Hc];   // 36 KB
  __shared__ float sc[NHEAD][Tc];    // 6 KB
  const int b = blockIdx.x;
  const int tid = threadIdx.x;
  for (int i = tid; i < NHEAD * Hc; i += 256)
    ((float*)Phs)[i] = bf2f(Pb[(size_t)b * NHEAD * Hc + i]);
  __syncthreads();
  const int t = tid & 127, hh = tid >> 7;
  const int h0 = hh * 6;
  float a6[6];
#pragma unroll
  for (int i = 0; i < 6; ++i) a6[i] = 0.f;
  const float* xr = utt + ((size_t)b * Tc + t) * Hc;
  for (int j = 0; j < Hc; j += 4) {
    const float4 xv = *(const float4*)(xr + j);
#pragma unroll
    for (int i = 0; i < 6; ++i) {
      a6[i] = fmaf(xv.x, Phs[h0 + i][j], a6[i]);
      a6[i] = fmaf(xv.y, Phs[h0 + i][j + 1], a6[i]);
      a6[i] = fmaf(xv.z, Phs[h0 + i][j + 2], a6[i]);
      a6[i] = fmaf(xv.w, Phs[h0 + i][j + 3], a6[i]);
    }
  }
#pragma unroll
  for (int i = 0; i < 6; ++i)
    sc[h0 + i][t] = (a6[i] + cqB[b * NHEAD + h0 + i]) * 0.125f;
  __syncthreads();
  const int w = tid >> 6, lane = tid & 63;
#pragma unroll
  for (int i = 0; i < 3; ++i) {
    const int h = w * 3 + i;
    const float s0 = sc[h][lane], s1 = sc[h][lane + 64];
    float m = fmaxf(s0, s1);
#pragma unroll
    for (int off = 32; off; off >>= 1) m = fmaxf(m, __shfl_xor(m, off));
    const float e0 = expf(s0 - m), e1 = expf(s1 - m);
    float s = e0 + e1;
#pragma unroll
    for (int off = 32; off; off >>= 1) s += __shfl_xor(s, off);
    const float inv = 1.f / s;
    Att[((size_t)b * NHEAD + h) * Tc + lane] = e0 * inv;
    Att[((size_t)b * NHEAD + h) * Tc + lane + 64] = e1 * inv;
  }
}

// block per b, 256 threads: U (LDS) = sum_t Att*utt; Xc = Wv.U + bv
__global__ __launch_bounds__(256) void attn_uxc_k(
    const float* __restrict__ Att, const float* __restrict__ utt,
    const float* __restrict__ Wv, const float* __restrict__ bv,
    float* __restrict__ Xc)
{
  __shared__ float As[NHEAD][Tc];
  __shared__ float Us[NHEAD * Hc];
  const int b = blockIdx.x;
  const int tid = threadIdx.x;
  for (int i = tid; i < NHEAD * Tc; i += 256)
    ((float*)As)[i] = Att[(size_t)b * NHEAD * Tc + i];
  __syncthreads();
  float acc[NHEAD][3];
#pragma unroll
  for (int h = 0; h < NHEAD; ++h)
#pragma unroll
    for (int q = 0; q < 3; ++q) acc[h][q] = 0.f;
  for (int t = 0; t < Tc; ++t) {
    const float* xr = utt + ((size_t)b * Tc + t) * Hc;
    const float x0 = xr[tid], x1 = xr[tid + 256], x2 = xr[tid + 512];
#pragma unroll
    for (int h = 0; h < NHEAD; ++h) {
      const float a = As[h][t];
      acc[h][0] = fmaf(a, x0, acc[h][0]);
      acc[h][1] = fmaf(a, x1, acc[h][1]);
      acc[h][2] = fmaf(a, x2, acc[h][2]);
    }
  }
#pragma unroll
  for (int h = 0; h < NHEAD; ++h)
#pragma unroll
    for (int q = 0; q < 3; ++q)
      Us[h * Hc + tid + q * 256] = acc[h][q];
  __syncthreads();
#pragma unroll
  for (int rr = 0; rr < 3; ++rr) {
    const int hd = tid + rr * 256;
    const int h = hd >> 6;
    const float* wr = Wv + (size_t)hd * Hc;
    const float* ub = Us + h * Hc;
    float a = 0.f;
    for (int j = 0; j < Hc; j += 4) {
      const float4 w4 = *(const float4*)(wr + j);
      a += w4.x * ub[j] + w4.y * ub[j + 1] + w4.z * ub[j + 2] + w4.w * ub[j + 3];
    }
    Xc[(size_t)b * Hc + hd] = a + bv[hd];
  }
}

// sequential LSTM step (unchanged math; Hch now fp32)
__global__ __launch_bounds__(512) void lstm_step_k(
    const float* __restrict__ Whh, const float* __restrict__ GXc,
    float* __restrict__ Hping, float* __restrict__ Hch,
    float* __restrict__ Cb, int t, int tl)
{
  __shared__ float hs[RHc * 16];
  __shared__ float red[2 * 256 * 4];
  const int blk = blockIdx.x;
  const int ut = blk & 31, bt = blk >> 5;
  const int tid = threadIdx.x;
  const int kh = tid >> 8;
  const int p = tid & 255;
  const int bl = p & 15, ul = p >> 4;
  const int b = bt * 16 + bl, u = ut * 16 + ul;
  float ai = 0.f, af = 0.f, ag = 0.f, ao = 0.f;
  if (t > 0) {
    const float* hprev = Hping + (size_t)((t & 1) ^ 1) * (Bc * RHc) + (size_t)(bt * 16) * RHc;
#pragma unroll
    for (int i = 0; i < 4; ++i) {
      const int idx = tid + i * 512;
      const int rr = idx & 15;
      const int c4 = (idx >> 4) << 2;
      const float4 hv = *(const float4*)(hprev + (size_t)rr * RHc + c4);
      hs[(c4 + 0) * 16 + rr] = hv.x;
      hs[(c4 + 1) * 16 + rr] = hv.y;
      hs[(c4 + 2) * 16 + rr] = hv.z;
      hs[(c4 + 3) * 16 + rr] = hv.w;
    }
    __syncthreads();
    const float* w0 = Whh + (size_t)u * RHc + kh * 256;
    const float* w1 = w0 + 512 * 512;
    const float* w2 = w1 + 512 * 512;
    const float* w3 = w2 + 512 * 512;
    const int hb = (kh * 256) * 16 + bl;
#pragma unroll 4
    for (int kk = 0; kk < 256; kk += 4) {
      const float4 wi = *(const float4*)(w0 + kk);
      const float4 wf = *(const float4*)(w1 + kk);
      const float4 wg = *(const float4*)(w2 + kk);
      const float4 wo = *(const float4*)(w3 + kk);
      const int hk = hb + kk * 16;
      const float h0 = hs[hk], h1 = hs[hk + 16], h2 = hs[hk + 32], h3 = hs[hk + 48];
      ai = fmaf(wi.x, h0, fmaf(wi.y, h1, fmaf(wi.z, h2, fmaf(wi.w, h3, ai))));
      af = fmaf(wf.x, h0, fmaf(wf.y, h1, fmaf(wf.z, h2, fmaf(wf.w, h3, af))));
      ag = fmaf(wg.x, h0, fmaf(wg.y, h1, fmaf(wg.z, h2, fmaf(wg.w, h3, ag))));
      ao = fmaf(wo.x, h0, fmaf(wo.y, h1, fmaf(wo.z, h2, fmaf(wo.w, h3, ao))));
    }
  }
  *(float4*)&red[((size_t)kh * 256 + p) * 4] = make_float4(ai, af, ag, ao);
  __syncthreads();
  if (kh == 0) {
    const float4 oth = *(const float4*)&red[(size_t)(256 + p) * 4];
    ai += oth.x; af += oth.y; ag += oth.z; ao += oth.w;
    const size_t gofs = ((size_t)tl * Bc + b) * G4c + u;
    const float gi = GXc[gofs] + ai;
    const float gf = GXc[gofs + 512] + af;
    const float gg = GXc[gofs + 1024] + ag;
    const float go = GXc[gofs + 1536] + ao;
    const float iv = sigmoidf_(gi);
    const float fv = sigmoidf_(gf);
    const float gv = tanhf(gg);
    const float ov = sigmoidf_(go);
    const size_t cidx = (size_t)b * RHc + u;
    float c = (t > 0) ? Cb[cidx] : 0.f;
    c = fmaf(fv, c, iv * gv);
    Cb[cidx] = c;
    const float hval = ov * tanhf(c);
    Hping[(size_t)(t & 1) * (Bc * RHc) + (size_t)b * RHc + u] = hval;
    Hch[((size_t)tl * Bc + b) * RHc + u] = hval;
  }
}

// one wave per (tl,b): y = h @ W_tag^T + b_tag, LayerNorm over NT=10
__global__ __launch_bounds__(256) void tag_ln_k(
    const float* __restrict__ Hch, const float* __restrict__ Wtag,
    const float* __restrict__ btag, const float* __restrict__ lng,
    const float* __restrict__ lnb, float* __restrict__ out, int t0)
{
  const int wid = (blockIdx.x * blockDim.x + threadIdx.x) >> 6;
  const int lane = threadIdx.x & 63;
  const int tl = wid >> 7, b = wid & 127;
  const int t = t0 + tl;
  const float* hp = Hch + ((size_t)tl * Bc + b) * RHc;
  float y[NTc];
#pragma unroll
  for (int j = 0; j < NTc; ++j) y[j] = 0.f;
  for (int k = lane; k < RHc; k += 64) {
    const float hv = hp[k];
#pragma unroll
    for (int j = 0; j < NTc; ++j)
      y[j] = fmaf(hv, Wtag[(size_t)j * RHc + k], y[j]);
  }
#pragma unroll
  for (int off = 32; off > 0; off >>= 1)
#pragma unroll
    for (int j = 0; j < NTc; ++j)
      y[j] += __shfl_xor(y[j], off);
  float mu = 0.f;
#pragma unroll
  for (int j = 0; j < NTc; ++j) { y[j] += btag[j]; mu += y[j]; }
  mu *= (1.0f / NTc);
  float var = 0.f;
#pragma unroll
  for (int j = 0; j < NTc; ++j) { const float d = y[j] - mu; var = fmaf(d, d, var); }
  var *= (1.0f / NTc);
  const float inv = rsqrtf(var + LNEPS);
  if (lane < NTc) {
    out[(size_t)b * NTc * Tc + (size_t)lane * Tc + t] =
        (y[lane] - mu) * inv * lng[lane] + lnb[lane];
  }
}

extern "C" void kernel_launch(void* const* d_in, const int* in_sizes, int n_in,
                              void* d_out, int out_size, void* d_ws, size_t ws_size,
                              hipStream_t stream)
{
  const float* slot = (const float*)d_in[0];
  const float* utt  = (const float*)d_in[1];
  const float* Wq = (const float*)d_in[2];   const float* bq = (const float*)d_in[3];
  const float* Wk = (const float*)d_in[4];   const float* bk = (const float*)d_in[5];
  const float* Wv = (const float*)d_in[6];   const float* bv = (const float*)d_in[7];
  const float* Wo = (const float*)d_in[8];   const float* bo = (const float*)d_in[9];
  const float* W_in = (const float*)d_in[10]; const float* b_in = (const float*)d_in[11];
  const float* W_ih = (const float*)d_in[12]; const float* W_hh = (const float*)d_in[13];
  const float* b_ih = (const float*)d_in[14]; const float* b_hh = (const float*)d_in[15];
  const float* W_tag = (const float*)d_in[16]; const float* b_tag = (const float*)d_in[17];
  const float* ln_g = (const float*)d_in[18]; const float* ln_b = (const float*)d_in[19];
  float* out = (float*)d_out;
  float* ws = (float*)d_ws;

  // adaptive chunk (floats): fixed = 1,805,824; per-chunk = 360,448
  int CHT = 16;
  while (CHT > 2 && 4ull * (1805824ull + 360448ull * (unsigned)CHT) > ws_size)
    CHT >>= 1;
  const int NCH = Tc / CHT;

  float* Xc    = ws;                         // 98304
  float* Xo    = Xc + 98304;                 // 98304
  float* bsum  = Xo + 98304;                 // 2048
  float* Cb    = bsum + 2048;                // 65536
  float* Att   = Cb + 65536;                 // 196608
  float* Hping = Att + 196608;               // 131072
  ushort* WinB = (ushort*)(Hping + 131072);  // 786432 us (393216 f)
  ushort* WihB = (ushort*)(ws + 985088);     // 1048576 us (524288 f)
  ushort* WoB  = (ushort*)(ws + 1509376);    // 589824 us (294912 f)
  float* cqB   = ws + 1804288;               // 1536
  // loop region (re-used): LINc bf16, GXc f32, Hch f32; Pb overlays it (pre-loop)
  ushort* LINc = (ushort*)(ws + 1805824);                    // 65536*CHT us
  float* GXc   = ws + 1805824 + (size_t)32768 * CHT;         // 262144*CHT f
  float* Hch   = GXc + (size_t)262144 * CHT;                 // 65536*CHT f
  ushort* Pb   = (ushort*)(ws + 1805824);                    // 1,179,648 us (overlay)

  // weight conversions + bias sum
  hipLaunchKernelGGL(cvt4_k, dim3(768), dim3(256), 0, stream, W_in, WinB, 196608);
  hipLaunchKernelGGL(cvt4_k, dim3(1024), dim3(256), 0, stream, W_ih, WihB, 262144);
  hipLaunchKernelGGL(cvt4_k, dim3(576), dim3(256), 0, stream, Wo, WoB, 147456);
  hipLaunchKernelGGL(bias_sum_k, dim3(8), dim3(256), 0, stream, b_ih, b_hh, bsum);

  // attention
  hipLaunchKernelGGL(fold_qp_k, dim3(Bc * NHEAD), dim3(256), 0, stream,
                     slot, Wq, bq, Wk, bk, Pb, cqB);
  hipLaunchKernelGGL(attn_scores2_k, dim3(Bc), dim3(256), 0, stream, Pb, cqB, utt, Att);
  hipLaunchKernelGGL(attn_uxc_k, dim3(Bc), dim3(256), 0, stream, Att, utt, Wv, bv, Xc);
  // Xo = Xc @ Wo^T + bo (bf16 MFMA)
  hipLaunchKernelGGL(bgemm_bt, dim3(6, 1), dim3(256), 0, stream,
                     (const void*)Xc, WoB, bo, (void*)Xo, 128, 768, 768, 0, 0,
                     (const float*)nullptr, (const float*)nullptr, 0);

  // chunked precompute + sequential LSTM + chunked tag/LN
  for (int tc = 0; tc < NCH; ++tc) {
    hipLaunchKernelGGL(bgemm_bt, dim3(4, CHT), dim3(256), 0, stream,
                       (const void*)nullptr, WinB, b_in, (void*)LINc,
                       CHT * Bc, 512, 1536, 1, 1, utt, Xo, tc * CHT);
    hipLaunchKernelGGL(bgemm_bt, dim3(16, CHT), dim3(256), 0, stream,
                       (const void*)LINc, WihB, bsum, (void*)GXc,
                       CHT * Bc, 2048, 512, 2, 0,
                       (const float*)nullptr, (const float*)nullptr, 0);
    for (int tl = 0; tl < CHT; ++tl)
      hipLaunchKernelGGL(lstm_step_k, dim3(256), dim3(512), 0, stream,
                         W_hh, GXc, Hping, Hch, Cb, tc * CHT + tl, tl);
    hipLaunchKernelGGL(tag_ln_k, dim3(CHT * 32), dim3(256), 0, stream,
                       Hch, W_tag, b_tag, ln_g, ln_b, out, tc * CHT);
  }
}